// Round 1
// baseline (341.524 us; speedup 1.0000x reference)
//
#include <hip/hip_runtime.h>

// PosEvalModel: embed-gather + GRU(L=128, N=3200) + proj + GRU(C=50, N=64) + final.
// Strategy:
//  K0: M2[384][129] = ctx_w_ih @ proj_w (+combined bias b2)    -- fold proj into ctx gi
//  K1: table[v][384] = ast_w_ih @ emb[v] + b_ih (+b_hh r,z)    -- fold W_ih into embedding (bf16, 77MB, L3-resident)
//  K2: ast recurrence: W_hh as MFMA B-frags in VGPRs, h fp32 in regs, LDS transpose buffer,
//      gi = gather from table, prefetched 1 step ahead; raw barriers (no vmcnt drain)
//  K3: cgi[c,b][384] = M2 @ [hT;ind] + b2 (one MFMA GEMM)
//  K4: ctx recurrence (same kernel template as K2, fp32 gi)
//  K5: final 64x3
// ws layout (needs ~83.6 MB): table@0, hT@76806144, cgi@78444544, M2@83359744, b2@83562496, cT@83564032

#define V_VOCAB 100008
#define L_DIM   128

typedef __attribute__((ext_vector_type(8))) short bf16x8;
typedef __attribute__((ext_vector_type(4))) float f32x4;

__device__ __forceinline__ unsigned pk_bf16(float lo, float hi){
  unsigned r;
  asm("v_cvt_pk_bf16_f32 %0, %1, %2" : "=v"(r) : "v"(lo), "v"(hi));
  return r;
}
__device__ __forceinline__ bf16x8 pack8(f32x4 a, f32x4 b){
  union { unsigned u[4]; bf16x8 v; } x;
  x.u[0] = pk_bf16(a[0], a[1]);
  x.u[1] = pk_bf16(a[2], a[3]);
  x.u[2] = pk_bf16(b[0], b[1]);
  x.u[3] = pk_bf16(b[2], b[3]);
  return x.v;
}
__device__ __forceinline__ float bf2f(unsigned bits){
  union { unsigned u; float f; } x; x.u = bits << 16; return x.f;
}
__device__ __forceinline__ unsigned short f2bf(float f){
  union { float f; unsigned u; } x; x.f = f;
  unsigned r = x.u + 0x7fffu + ((x.u >> 16) & 1u);
  return (unsigned short)(r >> 16);
}
__device__ __forceinline__ float fexp2(float x){ return __builtin_amdgcn_exp2f(x); }
__device__ __forceinline__ float frcp(float x){ return __builtin_amdgcn_rcpf(x); }
__device__ __forceinline__ float sigm(float x){ return frcp(1.f + fexp2(x * -1.44269504089f)); }
__device__ __forceinline__ float tanh_fast(float x){
  float t = fexp2(x * -2.88539008178f);        // e^{-2x}
  return (1.f - t) * frcp(1.f + t);
}
// swizzled LDS index for h buffer [16 rows][128 k] fp32; 32B granules XORed by row
__device__ __forceinline__ int hidx(int row, int k){
  return row*128 + ((((k >> 3) ^ row) & 15) * 8) + (k & 7);
}

// ---------------- K0: M2 = ctx_w_ih @ proj_w (+b2) ----------------
__global__ __launch_bounds__(256)
void m2_kernel(const float* __restrict__ wcih, const float* __restrict__ pw,
               const float* __restrict__ pb, const float* __restrict__ bcih,
               const float* __restrict__ bchh, float* __restrict__ M2,
               float* __restrict__ b2)
{
  int t = blockIdx.x*256 + threadIdx.x;
  if (t >= 384*130) return;
  int o = t / 130, kk = t % 130;
  const float* wr = wcih + o*128;
  if (kk < 129){
    float acc = 0.f;
    for (int m = 0; m < 128; ++m) acc += wr[m] * pw[m*129 + kk];
    M2[o*132 + kk] = acc;                       // padded stride 132
  } else {
    float acc = bcih[o] + (o < 256 ? bchh[o] : 0.f);
    for (int m = 0; m < 128; ++m) acc += wr[m] * pb[m];
    b2[o] = acc;
  }
}

// ---------------- K1: table[v][384] = W_ih @ emb[v] + biases (bf16) ----------------
__global__ __launch_bounds__(256)
void table_kernel(const float* __restrict__ emb, const float* __restrict__ wih,
                  const float* __restrict__ bih, const float* __restrict__ bhh,
                  unsigned short* __restrict__ table)
{
  const int tid = threadIdx.x;
  const int w = tid >> 6, lane = tid & 63, c = lane & 15, q = lane >> 4;
  const int gw = blockIdx.x*4 + w;
  const int vbase = gw * 64;
  if (vbase >= V_VOCAB) return;
  bf16x8 A[4][4];                               // 4 row-tiles x 4 k-tiles
#pragma unroll
  for (int rt = 0; rt < 4; ++rt)
#pragma unroll
    for (int kt = 0; kt < 4; ++kt){
      int va = vbase + rt*16 + c; if (va > V_VOCAB-1) va = V_VOCAB-1;
      const f32x4* p = (const f32x4*)(emb + (size_t)va*128 + kt*32 + q*8);
      A[rt][kt] = pack8(p[0], p[1]);
    }
#pragma unroll 1
  for (int ot = 0; ot < 24; ++ot){
    bf16x8 Bf[4];
#pragma unroll
    for (int kt = 0; kt < 4; ++kt){
      const f32x4* p = (const f32x4*)(wih + (ot*16 + c)*128 + kt*32 + q*8);
      Bf[kt] = pack8(p[0], p[1]);
    }
    f32x4 D[4];
#pragma unroll
    for (int rt = 0; rt < 4; ++rt) D[rt] = (f32x4){0.f,0.f,0.f,0.f};
#pragma unroll
    for (int kt = 0; kt < 4; ++kt)
#pragma unroll
      for (int rt = 0; rt < 4; ++rt)
        D[rt] = __builtin_amdgcn_mfma_f32_16x16x32_bf16(A[rt][kt], Bf[kt], D[rt], 0,0,0);
    int o = ot*16 + c;
    float bias = bih[o] + (ot < 16 ? bhh[o] : 0.f);   // fold b_hh for r,z gates only
#pragma unroll
    for (int rt = 0; rt < 4; ++rt)
#pragma unroll
      for (int r = 0; r < 4; ++r){
        int v = vbase + rt*16 + q*4 + r;
        if (v < V_VOCAB) table[(size_t)v*384 + o] = f2bf(D[rt][r] + bias);
      }
  }
}

// ---------------- K2/K4: GRU recurrence ----------------
// Block = 4 waves = 16 rows. Wave w owns k-slice [32w,32w+32) -> o-tiles {2w,2w+1, 8+2w,8+2w+1, 16+2w,16+2w+1}.
// W_hh B-frags live in VGPRs; h fp32 master in regs (D-layout) + swizzled LDS for A-frag rebuild.
template<int STEPS, bool TABLE_GI>
__global__ __launch_bounds__(256, 1)
void gru_kernel(const int* __restrict__ tok_ids,
                const unsigned short* __restrict__ gi_tab,
                const float* __restrict__ gi_f32,
                const float* __restrict__ whh,
                const float* __restrict__ bhh,
                const float* __restrict__ hinit,
                float* __restrict__ hout)
{
  __shared__ int   toks[2048];
  __shared__ float hbuf[2048];
  const int tid = threadIdx.x;
  const int w = tid >> 6, lane = tid & 63, c = lane & 15, q = lane >> 4;
  const int n0 = blockIdx.x * 16;

  if constexpr (TABLE_GI){
    for (int i = tid; i < 2048; i += 256) toks[i] = tok_ids[n0*L_DIM + i];
  }
  // W_hh fragments -> registers (B layout: col = lane&15 = o, k = kt*32 + q*8 + e)
  bf16x8 Bw[6][4];
#pragma unroll
  for (int g = 0; g < 3; ++g)
#pragma unroll
    for (int jj = 0; jj < 2; ++jj)
#pragma unroll
      for (int kt = 0; kt < 4; ++kt){
        int o = (g*8 + 2*w + jj)*16 + c;
        const f32x4* p = (const f32x4*)(whh + o*128 + kt*32 + q*8);
        Bw[g*2+jj][kt] = pack8(p[0], p[1]);
      }
  float bn[2], h_old[2][4];
#pragma unroll
  for (int jj = 0; jj < 2; ++jj){
    int kc = (2*w + jj)*16 + c;
    bn[jj] = bhh[256 + kc];                     // n-gate hidden bias (inside r*(...))
    float h0 = hinit[kc];
#pragma unroll
    for (int r = 0; r < 4; ++r) h_old[jj][r] = h0;
  }
  for (int i = tid; i < 2048; i += 256){
    int row = i >> 7, k = i & 127;
    hbuf[hidx(row, k)] = hinit[k];
  }
  __syncthreads();

  unsigned GA[6][4], GB[6][4];

  auto load_gi = [&](unsigned (&G)[6][4], int S){
    if constexpr (TABLE_GI){
      int tk[4];
#pragma unroll
      for (int r = 0; r < 4; ++r) tk[r] = toks[(q*4 + r)*L_DIM + S];
#pragma unroll
      for (int g = 0; g < 3; ++g)
#pragma unroll
        for (int jj = 0; jj < 2; ++jj)
#pragma unroll
          for (int r = 0; r < 4; ++r)
            G[g*2+jj][r] = gi_tab[(unsigned)tk[r]*384u + (unsigned)((g*8 + 2*w + jj)*16 + c)];
    } else {
#pragma unroll
      for (int g = 0; g < 3; ++g)
#pragma unroll
        for (int jj = 0; jj < 2; ++jj)
#pragma unroll
          for (int r = 0; r < 4; ++r){
            int rowg = S*64 + n0 + q*4 + r;
            G[g*2+jj][r] = __float_as_uint(gi_f32[rowg*384 + (g*8 + 2*w + jj)*16 + c]);
          }
    }
  };

  auto body = [&](int S, unsigned (&GC)[6][4], unsigned (&GN)[6][4]){
    // A-frags from swizzled LDS (row = c, k = kt*32 + q*8 + e)
    bf16x8 A[4];
#pragma unroll
    for (int kt = 0; kt < 4; ++kt){
      const f32x4* pa = (const f32x4*)&hbuf[hidx(c, kt*32 + q*8)];
      A[kt] = pack8(pa[0], pa[1]);
    }
    f32x4 D[6];
#pragma unroll
    for (int i = 0; i < 6; ++i) D[i] = (f32x4){0.f,0.f,0.f,0.f};
#pragma unroll
    for (int i = 0; i < 6; ++i)
#pragma unroll
      for (int kt = 0; kt < 4; ++kt)
        D[i] = __builtin_amdgcn_mfma_f32_16x16x32_bf16(A[kt], Bw[i][kt], D[i], 0,0,0);
    if (S + 1 < STEPS) load_gi(GN, S + 1);      // prefetch next step's gi (stays in flight across raw barriers)
    // gate math: D row = q*4+reg, col = c -> everything lane-local
#pragma unroll
    for (int jj = 0; jj < 2; ++jj)
#pragma unroll
      for (int r = 0; r < 4; ++r){
        float gr = TABLE_GI ? bf2f(GC[jj][r])   : __uint_as_float(GC[jj][r]);
        float gz = TABLE_GI ? bf2f(GC[2+jj][r]) : __uint_as_float(GC[2+jj][r]);
        float gn = TABLE_GI ? bf2f(GC[4+jj][r]) : __uint_as_float(GC[4+jj][r]);
        float ar = D[jj][r]   + gr;             // i_r + h_r (+biases folded)
        float az = D[2+jj][r] + gz;             // i_z + h_z
        float hn = D[4+jj][r] + bn[jj];         // h_n (b_hh_n separate: multiplied by r)
        float nn = tanh_fast(gn + sigm(ar)*hn);
        float z  = sigm(az);
        h_old[jj][r] = nn + z*(h_old[jj][r] - nn);
      }
    // raw barriers: lgkm drain only, vmcnt (gi prefetch) stays outstanding
    asm volatile("s_waitcnt lgkmcnt(0)" ::: "memory");
    __builtin_amdgcn_s_barrier();
#pragma unroll
    for (int jj = 0; jj < 2; ++jj)
#pragma unroll
      for (int r = 0; r < 4; ++r)
        hbuf[hidx(q*4 + r, (2*w + jj)*16 + c)] = h_old[jj][r];
    asm volatile("s_waitcnt lgkmcnt(0)" ::: "memory");
    __builtin_amdgcn_s_barrier();
  };

  load_gi(GA, 0);
#pragma unroll 1
  for (int s = 0; s < STEPS; s += 2){
    body(s,     GA, GB);
    body(s + 1, GB, GA);
  }
#pragma unroll
  for (int jj = 0; jj < 2; ++jj)
#pragma unroll
    for (int r = 0; r < 4; ++r)
      hout[(n0 + q*4 + r)*128 + (2*w + jj)*16 + c] = h_old[jj][r];
}

// ---------------- K3: cgi = M2 @ [hT;ind] + b2 ----------------
__global__ __launch_bounds__(256)
void cgi_kernel(const float* __restrict__ hT, const float* __restrict__ M2,
                const float* __restrict__ b2, float* __restrict__ cgi)
{
  const int tid = threadIdx.x;
  const int w = tid >> 6, lane = tid & 63, c = lane & 15, q = lane >> 4;
  const int n0 = (blockIdx.x*4 + w) * 16;       // 200 tiles of 16 rows (n = b*50+c)
  bf16x8 A[4];
#pragma unroll
  for (int kt = 0; kt < 4; ++kt){
    const f32x4* p = (const f32x4*)(hT + (n0 + c)*128 + kt*32 + q*8);
    A[kt] = pack8(p[0], p[1]);
  }
#pragma unroll 1
  for (int ot = 0; ot < 24; ++ot){
    f32x4 D = {0.f,0.f,0.f,0.f};
#pragma unroll
    for (int kt = 0; kt < 4; ++kt){
      const f32x4* p = (const f32x4*)(M2 + (ot*16 + c)*132 + kt*32 + q*8);
      bf16x8 Bf = pack8(p[0], p[1]);
      D = __builtin_amdgcn_mfma_f32_16x16x32_bf16(A[kt], Bf, D, 0,0,0);
    }
    int o = ot*16 + c;
    float bias = b2[o];
    float indv = M2[o*132 + 128];               // conclusion-indicator column
#pragma unroll
    for (int r = 0; r < 4; ++r){
      int n  = n0 + q*4 + r;
      int cc = n % 50, b = n / 50;
      float vv = D[r] + bias + (cc == 0 ? indv : 0.f);
      cgi[(cc*64 + b)*384 + o] = vv;            // stored [c][b] for the ctx scan
    }
  }
}

// ---------------- K5: out = cT @ final_w.T + final_b ----------------
__global__ __launch_bounds__(256)
void final_kernel(const float* __restrict__ cT, const float* __restrict__ fw,
                  const float* __restrict__ fb, float* __restrict__ out)
{
  int t = threadIdx.x;
  if (t >= 192) return;
  int b = t / 3, j = t % 3;
  const f32x4* cp = (const f32x4*)(cT + b*128);
  const f32x4* wp = (const f32x4*)(fw + j*128);
  float acc = fb[j];
#pragma unroll 4
  for (int i = 0; i < 32; ++i){
    f32x4 x = cp[i], y = wp[i];
    acc += x[0]*y[0] + x[1]*y[1] + x[2]*y[2] + x[3]*y[3];
  }
  out[t] = acc;
}

extern "C" void kernel_launch(void* const* d_in, const int* in_sizes, int n_in,
                              void* d_out, int out_size, void* d_ws, size_t ws_size,
                              hipStream_t stream)
{
  const int*   tok   = (const int*)  d_in[0];
  const float* emb   = (const float*)d_in[1];
  const float* awih  = (const float*)d_in[2];
  const float* awhh  = (const float*)d_in[3];
  const float* abih  = (const float*)d_in[4];
  const float* abhh  = (const float*)d_in[5];
  const float* ainit = (const float*)d_in[6];
  const float* cwih  = (const float*)d_in[7];
  const float* cwhh  = (const float*)d_in[8];
  const float* cbih  = (const float*)d_in[9];
  const float* cbhh  = (const float*)d_in[10];
  const float* cinit = (const float*)d_in[11];
  const float* pw    = (const float*)d_in[12];
  const float* pb    = (const float*)d_in[13];
  const float* fw    = (const float*)d_in[14];
  const float* fb    = (const float*)d_in[15];
  float* out = (float*)d_out;

  char* ws = (char*)d_ws;                       // needs ~83.6 MB
  unsigned short* table = (unsigned short*)(ws + 0);          // 100008*384*2 = 76,806,144
  float* hT  = (float*)(ws + 76806144);                       // 3200*128*4   =  1,638,400
  float* cgi = (float*)(ws + 78444544);                       // 3200*384*4   =  4,915,200
  float* M2  = (float*)(ws + 83359744);                       // 384*132*4    =    202,752
  float* b2  = (float*)(ws + 83562496);                       // 384*4
  float* cT  = (float*)(ws + 83564032);                       // 64*128*4

  m2_kernel   <<<195, 256, 0, stream>>>(cwih, pw, pb, cbih, cbhh, M2, b2);
  table_kernel<<<391, 256, 0, stream>>>(emb, awih, abih, abhh, table);
  gru_kernel<128, true ><<<200, 256, 0, stream>>>(tok, table, nullptr, awhh, abhh, ainit, hT);
  cgi_kernel  <<<50,  256, 0, stream>>>(hT, M2, b2, cgi);
  gru_kernel<50,  false><<<4,   256, 0, stream>>>(nullptr, nullptr, cgi, cwhh, cbhh, cinit, cT);
  final_kernel<<<1,   256, 0, stream>>>(cT, fw, fb, out);
}

// Round 2
// 271.129 us; speedup vs baseline: 1.2596x; 1.2596x over previous
//
#include <hip/hip_runtime.h>

// PosEvalModel: embed-gather + GRU(L=128, N=3200) + proj + GRU(C=50, N=64) + final.
//  K0: M2[384][129] = ctx_w_ih @ proj_w (+combined bias b2)
//  K1: table[v][384] = ast_w_ih @ emb[v] + b_ih (+b_hh r,z)  (bf16, 77MB, L3-resident)
//      v2: emb staged to LDS once, output staged to LDS, coalesced 16B flush
//  K2: ast recurrence v2: 8 waves/block (one o-tile per gate per wave), single barrier/step
//      via double-buffered h LDS, gather prefetch depth 2
//  K3: cgi[c,b][384] = M2 @ [hT;ind] + b2
//  K4: ctx recurrence (same template, fp32 gi) + fused final matmul epilogue

#define V_VOCAB 100008

typedef __attribute__((ext_vector_type(8))) short bf16x8;
typedef __attribute__((ext_vector_type(4))) float f32x4;

__device__ __forceinline__ unsigned pk_bf16(float lo, float hi){
  unsigned r;
  asm("v_cvt_pk_bf16_f32 %0, %1, %2" : "=v"(r) : "v"(lo), "v"(hi));
  return r;
}
__device__ __forceinline__ bf16x8 pack8(f32x4 a, f32x4 b){
  union { unsigned u[4]; bf16x8 v; } x;
  x.u[0] = pk_bf16(a[0], a[1]);
  x.u[1] = pk_bf16(a[2], a[3]);
  x.u[2] = pk_bf16(b[0], b[1]);
  x.u[3] = pk_bf16(b[2], b[3]);
  return x.v;
}
__device__ __forceinline__ float bf2f(unsigned bits){
  union { unsigned u; float f; } x; x.u = bits << 16; return x.f;
}
__device__ __forceinline__ unsigned short f2bf(float f){
  union { float f; unsigned u; } x; x.f = f;
  unsigned r = x.u + 0x7fffu + ((x.u >> 16) & 1u);
  return (unsigned short)(r >> 16);
}
__device__ __forceinline__ float fexp2(float x){ return __builtin_amdgcn_exp2f(x); }
__device__ __forceinline__ float frcp(float x){ return __builtin_amdgcn_rcpf(x); }
__device__ __forceinline__ float sigm(float x){ return frcp(1.f + fexp2(x * -1.44269504089f)); }
__device__ __forceinline__ float tanh_fast(float x){
  float t = fexp2(x * -2.88539008178f);        // e^{-2x}
  return (1.f - t) * frcp(1.f + t);
}
// swizzled LDS index for h buffer [16 rows][128 k] fp32; 32B granules XORed by row (incl row>>2
// so the 4 q-row-groups of the h-write land on distinct bank groups)
__device__ __forceinline__ int hidx(int row, int k){
  int swz = ((k >> 3) ^ row ^ (row >> 2)) & 15;
  return row*128 + swz*8 + (k & 7);
}

// ---------------- K0: M2 = ctx_w_ih @ proj_w (+b2) ----------------
__global__ __launch_bounds__(256)
void m2_kernel(const float* __restrict__ wcih, const float* __restrict__ pw,
               const float* __restrict__ pb, const float* __restrict__ bcih,
               const float* __restrict__ bchh, float* __restrict__ M2,
               float* __restrict__ b2)
{
  int t = blockIdx.x*256 + threadIdx.x;
  if (t >= 384*130) return;
  int o = t / 130, kk = t % 130;
  const float* wr = wcih + o*128;
  if (kk < 129){
    float acc = 0.f;
    for (int m = 0; m < 128; ++m) acc += wr[m] * pw[m*129 + kk];
    M2[o*132 + kk] = acc;                       // padded stride 132
  } else {
    float acc = bcih[o] + (o < 256 ? bchh[o] : 0.f);
    for (int m = 0; m < 128; ++m) acc += wr[m] * pb[m];
    b2[o] = acc;
  }
}

// ---------------- K1: table[v][384] = W_ih @ emb[v] + biases (bf16) ----------------
// Block = 4 waves, 64 vocab rows. Wave w computes o-tiles w*6..w*6+5.
// emb staged once to LDS (bf16, swizzled); outputs staged to padded LDS; coalesced flush.
__global__ __launch_bounds__(256, 2)
void table_kernel(const float* __restrict__ emb, const float* __restrict__ wih,
                  const float* __restrict__ bih, const float* __restrict__ bhh,
                  unsigned short* __restrict__ table)
{
  __shared__ unsigned short ebuf[64*128];       // 16KB  [row][k] bf16, 8-elem chunks swizzled
  __shared__ unsigned short obuf[64*408];       // ~51KB [row][384] bf16, padded to 408
  const int tid = threadIdx.x;
  const int w = tid >> 6, lane = tid & 63, c = lane & 15, q = lane >> 4;
  const int vbase = blockIdx.x * 64;

  // stage emb -> ebuf (each thread: one 8-float chunk per pass, coalesced 32B loads)
#pragma unroll
  for (int p = 0; p < 4; ++p){
    int chunk = p*256 + tid;                    // 1024 chunks = 64 rows x 16
    int row = chunk >> 4, k8 = chunk & 15;
    int va = vbase + row; if (va >= V_VOCAB) va = V_VOCAB - 1;
    const f32x4* src = (const f32x4*)(emb + (size_t)va*128 + k8*8);
    *(bf16x8*)&ebuf[(row*16 + (k8 ^ (row & 15)))*8] = pack8(src[0], src[1]);
  }
  __syncthreads();

  bf16x8 A[4][4];                               // 64 rows x K=128 fragments
#pragma unroll
  for (int rt = 0; rt < 4; ++rt)
#pragma unroll
    for (int kt = 0; kt < 4; ++kt)
      A[rt][kt] = *(const bf16x8*)&ebuf[((rt*16 + c)*16 + ((kt*4 + q) ^ c))*8];

#pragma unroll 1
  for (int j = 0; j < 6; ++j){
    int ot = w*6 + j, o = ot*16 + c;
    bf16x8 Bf[4];
#pragma unroll
    for (int kt = 0; kt < 4; ++kt){
      const f32x4* p = (const f32x4*)(wih + o*128 + kt*32 + q*8);
      Bf[kt] = pack8(p[0], p[1]);
    }
    float bias = bih[o] + (ot < 16 ? bhh[o] : 0.f);   // fold b_hh for r,z gates
    f32x4 D[4];
#pragma unroll
    for (int rt = 0; rt < 4; ++rt) D[rt] = (f32x4){0.f,0.f,0.f,0.f};
#pragma unroll
    for (int kt = 0; kt < 4; ++kt)
#pragma unroll
      for (int rt = 0; rt < 4; ++rt)
        D[rt] = __builtin_amdgcn_mfma_f32_16x16x32_bf16(A[rt][kt], Bf[kt], D[rt], 0,0,0);
#pragma unroll
    for (int rt = 0; rt < 4; ++rt)
#pragma unroll
      for (int r = 0; r < 4; ++r)
        obuf[(rt*16 + q*4 + r)*408 + o] = f2bf(D[rt][r] + bias);
  }
  __syncthreads();

  // flush: fully contiguous 16B/lane global stores
  const size_t gbase = (size_t)vbase * 384;
#pragma unroll
  for (int i = 0; i < 12; ++i){
    int e8 = i*256 + tid;                       // 3072 chunks = 64 rows x 48
    int row = e8 / 48, col8 = e8 % 48;
    if (vbase + row < V_VOCAB)
      *(bf16x8*)&table[gbase + row*384 + col8*8] =
        *(const bf16x8*)&obuf[row*408 + col8*8];
  }
}

// ---------------- K2/K4: GRU recurrence ----------------
// Block = 8 waves = 16 rows. Wave w owns k-slice [16w,16w+16) -> o-tiles {w, 8+w, 16+w}.
// Double-buffered hbuf -> single barrier/step. Gather prefetch depth 2 (2 buffers).
template<int STEPS, bool TABLE_GI, bool FINAL>
__global__ __launch_bounds__(512, 2)
void gru_kernel(const int* __restrict__ tok_ids,
                const unsigned short* __restrict__ gi_tab,
                const float* __restrict__ gi_f32,
                const float* __restrict__ whh,
                const float* __restrict__ bhh,
                const float* __restrict__ hinit,
                float* __restrict__ hout,
                const float* __restrict__ fw,
                const float* __restrict__ fb,
                float* __restrict__ outp)
{
  static_assert(STEPS % 2 == 0, "unroll-2 loop needs even STEPS");
  __shared__ float hbuf[2][2048];
  __shared__ int   toks[2048];
  const int tid = threadIdx.x;
  const int w = tid >> 6, lane = tid & 63, c = lane & 15, q = lane >> 4;
  const int n0 = blockIdx.x * 16;

  if constexpr (TABLE_GI){
    for (int i = tid; i < 2048; i += 512) toks[i] = tok_ids[n0*128 + i];
  }
  // W_hh fragments (B layout: col = lane&15 = o, k = kt*32 + q*8 + e)
  bf16x8 Bw[3][4];
#pragma unroll
  for (int g = 0; g < 3; ++g)
#pragma unroll
    for (int kt = 0; kt < 4; ++kt){
      int o = (g*8 + w)*16 + c;
      const f32x4* p = (const f32x4*)(whh + o*128 + kt*32 + q*8);
      Bw[g][kt] = pack8(p[0], p[1]);
    }
  const float bn = bhh[256 + w*16 + c];         // n-gate hidden bias (multiplied by r)
  float h_old[4];
  {
    float h0 = hinit[w*16 + c];
#pragma unroll
    for (int r = 0; r < 4; ++r) h_old[r] = h0;
  }
  for (int i = tid; i < 2048; i += 512){
    int row = i >> 7, k = i & 127;
    hbuf[0][hidx(row, k)] = hinit[k];
  }
  __syncthreads();

  unsigned GA[12], GB[12];

  auto load_gi = [&](unsigned (&G)[12], int S){
    if constexpr (TABLE_GI){
      int tk[4];
#pragma unroll
      for (int r = 0; r < 4; ++r) tk[r] = toks[(q*4 + r)*128 + S];
#pragma unroll
      for (int g = 0; g < 3; ++g)
#pragma unroll
        for (int r = 0; r < 4; ++r)
          G[g*4+r] = gi_tab[(unsigned)tk[r]*384u + (unsigned)((g*8 + w)*16 + c)];
    } else {
#pragma unroll
      for (int g = 0; g < 3; ++g)
#pragma unroll
        for (int r = 0; r < 4; ++r)
          G[g*4+r] = __float_as_uint(gi_f32[(S*64 + n0 + q*4 + r)*384 + (g*8 + w)*16 + c]);
    }
  };

  auto body = [&](int S, unsigned (&G)[12]){
    const int cur = S & 1, nxt = cur ^ 1;
    // A-frags from swizzled LDS (row = c, k = kt*32 + q*8)
    bf16x8 A[4];
#pragma unroll
    for (int kt = 0; kt < 4; ++kt){
      const f32x4* pa = (const f32x4*)&hbuf[cur][hidx(c, kt*32 + q*8)];
      A[kt] = pack8(pa[0], pa[1]);
    }
    f32x4 D[3];
#pragma unroll
    for (int g = 0; g < 3; ++g) D[g] = (f32x4){0.f,0.f,0.f,0.f};
#pragma unroll
    for (int g = 0; g < 3; ++g)
#pragma unroll
      for (int kt = 0; kt < 4; ++kt)
        D[g] = __builtin_amdgcn_mfma_f32_16x16x32_bf16(A[kt], Bw[g][kt], D[g], 0,0,0);
    // gate math: D row = q*4+r, col = c -> lane-local
#pragma unroll
    for (int r = 0; r < 4; ++r){
      float gr = TABLE_GI ? bf2f(G[r])    : __uint_as_float(G[r]);
      float gz = TABLE_GI ? bf2f(G[4+r])  : __uint_as_float(G[4+r]);
      float gn = TABLE_GI ? bf2f(G[8+r])  : __uint_as_float(G[8+r]);
      float ar = D[0][r] + gr;
      float az = D[1][r] + gz;
      float hn = D[2][r] + bn;
      float nn = tanh_fast(gn + sigm(ar)*hn);
      float z  = sigm(az);
      h_old[r] = nn + z*(h_old[r] - nn);
    }
    // refill the buffer just consumed with step S+2 (2-step-deep prefetch, in flight
    // across the barrier — vmcnt never drained in the loop)
    if (S + 2 < STEPS) load_gi(G, S + 2);
#pragma unroll
    for (int r = 0; r < 4; ++r)
      hbuf[nxt][hidx(q*4 + r, w*16 + c)] = h_old[r];
    asm volatile("s_waitcnt lgkmcnt(0)" ::: "memory");
    __builtin_amdgcn_s_barrier();
  };

  load_gi(GA, 0);
  load_gi(GB, 1);
#pragma unroll 1
  for (int s = 0; s < STEPS; s += 2){
    body(s,     GA);
    body(s + 1, GB);
  }

  if constexpr (FINAL){
    // fused final: out[b][j] = h[b] . fw[j] + fb[j]   (h in hbuf[STEPS&1], post-barrier)
    if (tid < 48){
      int row = tid / 3, j = tid % 3;
      float acc = fb[j];
      const int cur = STEPS & 1;
      for (int k = 0; k < 128; ++k)
        acc += hbuf[cur][hidx(row, k)] * fw[j*128 + k];
      outp[(n0 + row)*3 + j] = acc;
    }
  } else {
#pragma unroll
    for (int r = 0; r < 4; ++r)
      hout[(n0 + q*4 + r)*128 + w*16 + c] = h_old[r];
  }
}

// ---------------- K3: cgi = M2 @ [hT;ind] + b2 ----------------
__global__ __launch_bounds__(256)
void cgi_kernel(const float* __restrict__ hT, const float* __restrict__ M2,
                const float* __restrict__ b2, float* __restrict__ cgi)
{
  const int tid = threadIdx.x;
  const int w = tid >> 6, lane = tid & 63, c = lane & 15, q = lane >> 4;
  const int n0 = (blockIdx.x*4 + w) * 16;       // 200 tiles of 16 rows (n = b*50+c)
  bf16x8 A[4];
#pragma unroll
  for (int kt = 0; kt < 4; ++kt){
    const f32x4* p = (const f32x4*)(hT + (n0 + c)*128 + kt*32 + q*8);
    A[kt] = pack8(p[0], p[1]);
  }
#pragma unroll 1
  for (int ot = 0; ot < 24; ++ot){
    f32x4 D = {0.f,0.f,0.f,0.f};
#pragma unroll
    for (int kt = 0; kt < 4; ++kt){
      const f32x4* p = (const f32x4*)(M2 + (ot*16 + c)*132 + kt*32 + q*8);
      bf16x8 Bf = pack8(p[0], p[1]);
      D = __builtin_amdgcn_mfma_f32_16x16x32_bf16(A[kt], Bf, D, 0,0,0);
    }
    int o = ot*16 + c;
    float bias = b2[o];
    float indv = M2[o*132 + 128];               // conclusion-indicator column
#pragma unroll
    for (int r = 0; r < 4; ++r){
      int n  = n0 + q*4 + r;
      int cc = n % 50, b = n / 50;
      float vv = D[r] + bias + (cc == 0 ? indv : 0.f);
      cgi[(cc*64 + b)*384 + o] = vv;            // stored [c][b] for the ctx scan
    }
  }
}

extern "C" void kernel_launch(void* const* d_in, const int* in_sizes, int n_in,
                              void* d_out, int out_size, void* d_ws, size_t ws_size,
                              hipStream_t stream)
{
  const int*   tok   = (const int*)  d_in[0];
  const float* emb   = (const float*)d_in[1];
  const float* awih  = (const float*)d_in[2];
  const float* awhh  = (const float*)d_in[3];
  const float* abih  = (const float*)d_in[4];
  const float* abhh  = (const float*)d_in[5];
  const float* ainit = (const float*)d_in[6];
  const float* cwih  = (const float*)d_in[7];
  const float* cwhh  = (const float*)d_in[8];
  const float* cbih  = (const float*)d_in[9];
  const float* cbhh  = (const float*)d_in[10];
  const float* cinit = (const float*)d_in[11];
  const float* pw    = (const float*)d_in[12];
  const float* pb    = (const float*)d_in[13];
  const float* fw    = (const float*)d_in[14];
  const float* fb    = (const float*)d_in[15];
  float* out = (float*)d_out;

  char* ws = (char*)d_ws;                       // needs ~83.6 MB
  unsigned short* table = (unsigned short*)(ws + 0);          // 100008*384*2 = 76,806,144
  float* hT  = (float*)(ws + 76806144);                       // 3200*128*4   =  1,638,400
  float* cgi = (float*)(ws + 78444544);                       // 3200*384*4   =  4,915,200
  float* M2  = (float*)(ws + 83359744);                       // 384*132*4    =    202,752
  float* b2  = (float*)(ws + 83562496);                       // 384*4
  // (cT slot no longer needed; final fused into ctx gru)

  m2_kernel   <<<195,  256, 0, stream>>>(cwih, pw, pb, cbih, cbhh, M2, b2);
  table_kernel<<<1563, 256, 0, stream>>>(emb, awih, abih, abhh, table);
  gru_kernel<128, true,  false><<<200, 512, 0, stream>>>(tok, table, nullptr, awhh, abhh,
                                                         ainit, hT, nullptr, nullptr, nullptr);
  cgi_kernel  <<<50,   256, 0, stream>>>(hT, M2, b2, cgi);
  gru_kernel<50,  false, true ><<<4,   512, 0, stream>>>(nullptr, nullptr, cgi, cwhh, cbhh,
                                                         cinit, nullptr, fw, fb, out);
}

// Round 3
// 258.670 us; speedup vs baseline: 1.3203x; 1.0482x over previous
//
#include <hip/hip_runtime.h>

// PosEvalModel: embed-gather + GRU(L=128, N=3200) + proj + GRU(C=50, N=64) + final.
//  K0: M2[384][129] = ctx_w_ih @ proj_w (+combined bias b2)
//  K1: table[v][384] = ast_w_ih @ emb[v] + b_ih (+b_hh r,z)  (bf16, 77MB, L3-resident)
//      v3: 32 rows/block, 34KB LDS, 4 blocks/CU
//  K2: ast recurrence v3: 8 waves/block, single barrier/step, h stored bf16 in LDS,
//      gi fed as MFMA C-operand, gather prefetch depth 4 (vmcnt never drained)
//  K3: cgi[c,b][384] = M2 @ [hT;ind] + b2
//  K4: ctx recurrence (same template, fp32 gi, depth 2) + fused final matmul epilogue

#define V_VOCAB 100008

typedef __attribute__((ext_vector_type(8))) short bf16x8;
typedef __attribute__((ext_vector_type(4))) float f32x4;

__device__ __forceinline__ unsigned pk_bf16(float lo, float hi){
  unsigned r;
  asm("v_cvt_pk_bf16_f32 %0, %1, %2" : "=v"(r) : "v"(lo), "v"(hi));
  return r;
}
__device__ __forceinline__ unsigned short bf1(float x){   // single f32->bf16 (RNE)
  return (unsigned short)pk_bf16(x, x);
}
__device__ __forceinline__ bf16x8 pack8(f32x4 a, f32x4 b){
  union { unsigned u[4]; bf16x8 v; } x;
  x.u[0] = pk_bf16(a[0], a[1]);
  x.u[1] = pk_bf16(a[2], a[3]);
  x.u[2] = pk_bf16(b[0], b[1]);
  x.u[3] = pk_bf16(b[2], b[3]);
  return x.v;
}
__device__ __forceinline__ float bf2f(unsigned bits){
  union { unsigned u; float f; } x; x.u = bits << 16; return x.f;
}
__device__ __forceinline__ float fexp2(float x){ return __builtin_amdgcn_exp2f(x); }
__device__ __forceinline__ float frcp(float x){ return __builtin_amdgcn_rcpf(x); }
__device__ __forceinline__ float sigm(float x){ return frcp(1.f + fexp2(x * -1.44269504089f)); }
__device__ __forceinline__ float tanh_fast(float x){
  float t = fexp2(x * -2.88539008178f);        // e^{-2x}
  return (1.f - t) * frcp(1.f + t);
}
// element index of the 8-elem chunk (row, ch=k>>3) in a 16x128 bf16 h-tile, swizzled so
// A-frag reads (row=c) hit all 8 16B slots uniformly and h-writes are conflict-free
__device__ __forceinline__ int hchunk(int row, int ch){
  return row*128 + ((ch ^ row ^ (row >> 2)) & 15)*8;
}

// ---------------- K0: M2 = ctx_w_ih @ proj_w (+b2) ----------------
__global__ __launch_bounds__(256)
void m2_kernel(const float* __restrict__ wcih, const float* __restrict__ pw,
               const float* __restrict__ pb, const float* __restrict__ bcih,
               const float* __restrict__ bchh, float* __restrict__ M2,
               float* __restrict__ b2)
{
  int t = blockIdx.x*256 + threadIdx.x;
  if (t >= 384*130) return;
  int o = t / 130, kk = t % 130;
  const float* wr = wcih + o*128;
  if (kk < 129){
    float acc = 0.f;
    for (int m = 0; m < 128; ++m) acc += wr[m] * pw[m*129 + kk];
    M2[o*132 + kk] = acc;                       // padded stride 132
  } else {
    float acc = bcih[o] + (o < 256 ? bchh[o] : 0.f);
    for (int m = 0; m < 128; ++m) acc += wr[m] * pb[m];
    b2[o] = acc;
  }
}

// ---------------- K1: table[v][384] = W_ih @ emb[v] + biases (bf16) ----------------
// Block = 4 waves, 32 vocab rows. Wave w computes o-tiles w*6..w*6+5 (2 row-tiles each).
__global__ __launch_bounds__(256, 4)
void table_kernel(const float* __restrict__ emb, const float* __restrict__ wih,
                  const float* __restrict__ bih, const float* __restrict__ bhh,
                  unsigned short* __restrict__ table)
{
  __shared__ unsigned short ebuf[32*128];       // 8KB   [row][k] bf16, chunk-swizzled
  __shared__ unsigned short obuf[32*408];       // 25.5KB [row][384] bf16, padded to 408
  const int tid = threadIdx.x;
  const int w = tid >> 6, lane = tid & 63, c = lane & 15, q = lane >> 4;
  const int vbase = blockIdx.x * 32;

  // stage emb -> ebuf (512 chunks = 32 rows x 16; coalesced 32B loads)
#pragma unroll
  for (int p = 0; p < 2; ++p){
    int chunk = p*256 + tid;
    int row = chunk >> 4, k8 = chunk & 15;
    int va = vbase + row; if (va >= V_VOCAB) va = V_VOCAB - 1;
    const f32x4* src = (const f32x4*)(emb + (size_t)va*128 + k8*8);
    *(bf16x8*)&ebuf[(row*16 + (k8 ^ (row & 15)))*8] = pack8(src[0], src[1]);
  }
  __syncthreads();

  bf16x8 A[2][4];                               // 32 rows x K=128 fragments
#pragma unroll
  for (int rt = 0; rt < 2; ++rt)
#pragma unroll
    for (int kt = 0; kt < 4; ++kt)
      A[rt][kt] = *(const bf16x8*)&ebuf[((rt*16 + c)*16 + ((kt*4 + q) ^ c))*8];

#pragma unroll 1
  for (int j = 0; j < 6; ++j){
    int ot = w*6 + j, o = ot*16 + c;
    bf16x8 Bf[4];
#pragma unroll
    for (int kt = 0; kt < 4; ++kt){
      const f32x4* p = (const f32x4*)(wih + o*128 + kt*32 + q*8);
      Bf[kt] = pack8(p[0], p[1]);
    }
    float bias = bih[o] + (ot < 16 ? bhh[o] : 0.f);   // fold b_hh for r,z gates
    f32x4 D[2];
#pragma unroll
    for (int rt = 0; rt < 2; ++rt) D[rt] = (f32x4){0.f,0.f,0.f,0.f};
#pragma unroll
    for (int kt = 0; kt < 4; ++kt)
#pragma unroll
      for (int rt = 0; rt < 2; ++rt)
        D[rt] = __builtin_amdgcn_mfma_f32_16x16x32_bf16(A[rt][kt], Bf[kt], D[rt], 0,0,0);
#pragma unroll
    for (int rt = 0; rt < 2; ++rt)
#pragma unroll
      for (int r = 0; r < 4; ++r)
        obuf[(rt*16 + q*4 + r)*408 + o] = bf1(D[rt][r] + bias);
  }
  __syncthreads();

  // flush: fully contiguous 16B/lane global stores (1536 chunks = 32 rows x 48)
  const size_t gbase = (size_t)vbase * 384;
#pragma unroll
  for (int i = 0; i < 6; ++i){
    int e8 = i*256 + tid;
    int row = e8 / 48, col8 = e8 % 48;
    if (vbase + row < V_VOCAB)
      *(bf16x8*)&table[gbase + row*384 + col8*8] =
        *(const bf16x8*)&obuf[row*408 + col8*8];
  }
}

// ---------------- K2/K4: GRU recurrence ----------------
// Block = 8 waves = 16 rows. Wave w owns k-slice [16w,16w+16) -> o-tiles {w, 8+w, 16+w}.
// h stored bf16 in double-buffered LDS (1 barrier/step); gi fed as MFMA C-operand;
// gather prefetch DEPTH-deep (refill-consumed-buffer pipeline, vmcnt never drained).
template<int STEPS, int DEPTH, bool TABLE_GI, bool FINAL>
__global__ __launch_bounds__(512, 1)
void gru_kernel(const int* __restrict__ tok_ids,
                const unsigned short* __restrict__ gi_tab,
                const float* __restrict__ gi_f32,
                const float* __restrict__ whh,
                const float* __restrict__ bhh,
                const float* __restrict__ hinit,
                float* __restrict__ hout,
                const float* __restrict__ fw,
                const float* __restrict__ fb,
                float* __restrict__ outp)
{
  static_assert(STEPS % DEPTH == 0, "loop unrolls by DEPTH");
  __shared__ unsigned short hbuf[2][2048];      // [buf][16 rows x 128 k] bf16, swizzled
  __shared__ int toks[2048];                    // token byte-offsets into table
  const int tid = threadIdx.x;
  const int w = tid >> 6, lane = tid & 63, c = lane & 15, q = lane >> 4;
  const int n0 = blockIdx.x * 16;

  if constexpr (TABLE_GI){
    for (int i = tid; i < 2048; i += 512) toks[i] = tok_ids[n0*128 + i] * 768;
  }
  // W_hh fragments (B layout: col = lane&15 = o, k = kt*32 + q*8 + e)
  bf16x8 Bw[3][4];
#pragma unroll
  for (int g = 0; g < 3; ++g)
#pragma unroll
    for (int kt = 0; kt < 4; ++kt){
      int o = (g*8 + w)*16 + c;
      const f32x4* p = (const f32x4*)(whh + o*128 + kt*32 + q*8);
      Bw[g][kt] = pack8(p[0], p[1]);
    }
  const float bn = bhh[256 + w*16 + c];         // n-gate hidden bias (multiplied by r)
  float h_old[4];
  {
    float h0 = hinit[w*16 + c];
#pragma unroll
    for (int r = 0; r < 4; ++r) h_old[r] = h0;
  }
  for (int i = tid; i < 2048; i += 512){
    int row = i >> 7, k = i & 127;
    hbuf[0][hchunk(row, k >> 3) + (k & 7)] = bf1(hinit[k]);
  }
  __syncthreads();

  const char* tb = (const char*)gi_tab + (w*16 + c)*2;  // per-thread gather base

  unsigned G[DEPTH][12];

  auto load_gi = [&](int d, int S){
    if constexpr (TABLE_GI){
#pragma unroll
      for (int r = 0; r < 4; ++r){
        const unsigned short* p = (const unsigned short*)(tb + toks[(q*4 + r)*128 + S]);
        G[d][r]     = p[0];                     // r-gate   (+256B, +512B fold to imm offs)
        G[d][4 + r] = p[128];                   // z-gate
        G[d][8 + r] = p[256];                   // n-gate
      }
    } else {
#pragma unroll
      for (int r = 0; r < 4; ++r){
        const float* p = gi_f32 + (S*64 + n0 + q*4 + r)*384 + w*16 + c;
        G[d][r]     = __float_as_uint(p[0]);
        G[d][4 + r] = __float_as_uint(p[128]);
        G[d][8 + r] = __float_as_uint(p[256]);
      }
    }
  };

  auto body = [&](int S, int d){
    const int cur = S & 1, nxt = cur ^ 1;
    // A-frags straight from bf16 LDS (row = c, k = kt*32 + q*8 .. +7)
    bf16x8 A[4];
#pragma unroll
    for (int kt = 0; kt < 4; ++kt)
      A[kt] = *(const bf16x8*)&hbuf[cur][hchunk(c, kt*4 + q)];
    // C-operand = gi (r,z) and bn (n): saves zero-init movs and the post-adds
    f32x4 D[3];
#pragma unroll
    for (int r = 0; r < 4; ++r){
      D[0][r] = TABLE_GI ? bf2f(G[d][r])     : __uint_as_float(G[d][r]);
      D[1][r] = TABLE_GI ? bf2f(G[d][4 + r]) : __uint_as_float(G[d][4 + r]);
      D[2][r] = bn;
    }
#pragma unroll
    for (int g = 0; g < 3; ++g)
#pragma unroll
      for (int kt = 0; kt < 4; ++kt)
        D[g] = __builtin_amdgcn_mfma_f32_16x16x32_bf16(A[kt], Bw[g][kt], D[g], 0,0,0);
    // gate math: D row = q*4+r, col = c -> lane-local
#pragma unroll
    for (int r = 0; r < 4; ++r){
      float gn = TABLE_GI ? bf2f(G[d][8 + r]) : __uint_as_float(G[d][8 + r]);
      float rr = sigm(D[0][r]);
      float z  = sigm(D[1][r]);
      float nn = tanh_fast(gn + rr * D[2][r]);
      h_old[r] = nn + z*(h_old[r] - nn);
    }
    // refill the buffer just consumed with step S+DEPTH (stays in flight across barriers)
    if (S + DEPTH < STEPS) load_gi(d, S + DEPTH);
#pragma unroll
    for (int r = 0; r < 4; ++r)
      hbuf[nxt][hchunk(q*4 + r, w*2 + (c >> 3)) + (c & 7)] = bf1(h_old[r]);
    asm volatile("s_waitcnt lgkmcnt(0)" ::: "memory");
    __builtin_amdgcn_s_barrier();
  };

#pragma unroll
  for (int d = 0; d < DEPTH; ++d) load_gi(d, d);
#pragma unroll 1
  for (int s = 0; s < STEPS; s += DEPTH){
#pragma unroll
    for (int d = 0; d < DEPTH; ++d) body(s + d, d);
  }

  if constexpr (FINAL){
    // fused final: out[b][j] = h[b] . fw[j] + fb[j]   (h in hbuf[STEPS&1], post-barrier)
    if (tid < 48){
      int row = tid / 3, j = tid % 3;
      float acc = fb[j];
      const int cur = STEPS & 1;
      for (int k = 0; k < 128; ++k)
        acc += bf2f(hbuf[cur][hchunk(row, k >> 3) + (k & 7)]) * fw[j*128 + k];
      outp[(n0 + row)*3 + j] = acc;
    }
  } else {
#pragma unroll
    for (int r = 0; r < 4; ++r)
      hout[(n0 + q*4 + r)*128 + w*16 + c] = h_old[r];
  }
}

// ---------------- K3: cgi = M2 @ [hT;ind] + b2 ----------------
__global__ __launch_bounds__(256)
void cgi_kernel(const float* __restrict__ hT, const float* __restrict__ M2,
                const float* __restrict__ b2, float* __restrict__ cgi)
{
  const int tid = threadIdx.x;
  const int w = tid >> 6, lane = tid & 63, c = lane & 15, q = lane >> 4;
  const int n0 = (blockIdx.x*4 + w) * 16;       // 200 tiles of 16 rows (n = b*50+c)
  bf16x8 A[4];
#pragma unroll
  for (int kt = 0; kt < 4; ++kt){
    const f32x4* p = (const f32x4*)(hT + (n0 + c)*128 + kt*32 + q*8);
    A[kt] = pack8(p[0], p[1]);
  }
#pragma unroll 1
  for (int ot = 0; ot < 24; ++ot){
    f32x4 D = {0.f,0.f,0.f,0.f};
#pragma unroll
    for (int kt = 0; kt < 4; ++kt){
      const f32x4* p = (const f32x4*)(M2 + (ot*16 + c)*132 + kt*32 + q*8);
      bf16x8 Bf = pack8(p[0], p[1]);
      D = __builtin_amdgcn_mfma_f32_16x16x32_bf16(A[kt], Bf, D, 0,0,0);
    }
    int o = ot*16 + c;
    float bias = b2[o];
    float indv = M2[o*132 + 128];               // conclusion-indicator column
#pragma unroll
    for (int r = 0; r < 4; ++r){
      int n  = n0 + q*4 + r;
      int cc = n % 50, b = n / 50;
      float vv = D[r] + bias + (cc == 0 ? indv : 0.f);
      cgi[(cc*64 + b)*384 + o] = vv;            // stored [c][b] for the ctx scan
    }
  }
}

extern "C" void kernel_launch(void* const* d_in, const int* in_sizes, int n_in,
                              void* d_out, int out_size, void* d_ws, size_t ws_size,
                              hipStream_t stream)
{
  const int*   tok   = (const int*)  d_in[0];
  const float* emb   = (const float*)d_in[1];
  const float* awih  = (const float*)d_in[2];
  const float* awhh  = (const float*)d_in[3];
  const float* abih  = (const float*)d_in[4];
  const float* abhh  = (const float*)d_in[5];
  const float* ainit = (const float*)d_in[6];
  const float* cwih  = (const float*)d_in[7];
  const float* cwhh  = (const float*)d_in[8];
  const float* cbih  = (const float*)d_in[9];
  const float* cbhh  = (const float*)d_in[10];
  const float* cinit = (const float*)d_in[11];
  const float* pw    = (const float*)d_in[12];
  const float* pb    = (const float*)d_in[13];
  const float* fw    = (const float*)d_in[14];
  const float* fb    = (const float*)d_in[15];
  float* out = (float*)d_out;

  char* ws = (char*)d_ws;                       // needs ~83.6 MB
  unsigned short* table = (unsigned short*)(ws + 0);          // 100008*384*2 = 76,806,144
  float* hT  = (float*)(ws + 76806144);                       // 3200*128*4   =  1,638,400
  float* cgi = (float*)(ws + 78444544);                       // 3200*384*4   =  4,915,200
  float* M2  = (float*)(ws + 83359744);                       // 384*132*4    =    202,752
  float* b2  = (float*)(ws + 83562496);                       // 384*4

  m2_kernel   <<<195,  256, 0, stream>>>(cwih, pw, pb, cbih, cbhh, M2, b2);
  table_kernel<<<3126, 256, 0, stream>>>(emb, awih, abih, abhh, table);
  gru_kernel<128, 4, true,  false><<<200, 512, 0, stream>>>(tok, table, nullptr, awhh, abhh,
                                                            ainit, hT, nullptr, nullptr, nullptr);
  cgi_kernel  <<<50,   256, 0, stream>>>(hT, M2, b2, cgi);
  gru_kernel<50,  2, false, true ><<<4,   512, 0, stream>>>(nullptr, nullptr, cgi, cwhh, cbhh,
                                                            cinit, nullptr, fw, fb, out);
}

// Round 7
// 253.233 us; speedup vs baseline: 1.3487x; 1.0215x over previous
//
#include <hip/hip_runtime.h>

// PosEvalModel: embed-gather + GRU(L=128, N=3200) + proj + GRU(C=50, N=64) + final.
//  K0 m2:    M2[384][129] = ctx_w_ih @ proj_w (+b2)
//  K1 table: table[v][384] = ast_w_ih @ emb[v] + b_ih (+b_hh r,z)  (bf16, 77MB)  [r3-v3 exact]
//  K2 gru<TABLE>: ast recurrence v4: the 12 scattered 2B gi-gathers/thread replaced by
//      coalesced staging of the step's 16 token rows (3 x u64/thread) -> regs -> LDS
//      (776B-stride tile, conflict-free reads), 3-step pipeline, 1 barrier/step.
//  K3 cgi:   cgi[c,b][384] = M2 @ [hT;ind] + b2
//  K4 gru<!TABLE>: ctx recurrence (r3-exact) + fused final matmul epilogue

#define V_VOCAB 100008

typedef __attribute__((ext_vector_type(8))) short bf16x8;
typedef __attribute__((ext_vector_type(4))) float f32x4;

__device__ __forceinline__ unsigned pk_bf16(float lo, float hi){
  unsigned r;
  asm("v_cvt_pk_bf16_f32 %0, %1, %2" : "=v"(r) : "v"(lo), "v"(hi));
  return r;
}
__device__ __forceinline__ unsigned short bf1(float x){   // f32->bf16 via HW cvt
  return (unsigned short)pk_bf16(x, x);
}
__device__ __forceinline__ bf16x8 pack8(f32x4 a, f32x4 b){
  union { unsigned u[4]; bf16x8 v; } x;
  x.u[0] = pk_bf16(a[0], a[1]);
  x.u[1] = pk_bf16(a[2], a[3]);
  x.u[2] = pk_bf16(b[0], b[1]);
  x.u[3] = pk_bf16(b[2], b[3]);
  return x.v;
}
__device__ __forceinline__ float bf2f(unsigned bits){
  union { unsigned u; float f; } x; x.u = bits << 16; return x.f;
}
__device__ __forceinline__ float fexp2(float x){ return __builtin_amdgcn_exp2f(x); }
__device__ __forceinline__ float frcp(float x){ return __builtin_amdgcn_rcpf(x); }
__device__ __forceinline__ float sigm(float x){ return frcp(1.f + fexp2(x * -1.44269504089f)); }
__device__ __forceinline__ float tanh_fast(float x){
  float t = fexp2(x * -2.88539008178f);        // e^{-2x}
  return (1.f - t) * frcp(1.f + t);
}
// element index of the 8-elem chunk (row, ch=k>>3) in a 16x128 bf16 h-tile, swizzled
__device__ __forceinline__ int hchunk(int row, int ch){
  return row*128 + ((ch ^ row ^ (row >> 2)) & 15)*8;
}

// ---------------- K0: M2 = ctx_w_ih @ proj_w (+b2) ----------------
__global__ __launch_bounds__(256)
void m2_kernel(const float* __restrict__ wcih, const float* __restrict__ pw,
               const float* __restrict__ pb, const float* __restrict__ bcih,
               const float* __restrict__ bchh, float* __restrict__ M2,
               float* __restrict__ b2)
{
  int t = blockIdx.x*256 + threadIdx.x;
  if (t >= 384*130) return;
  int o = t / 130, kk = t % 130;
  const float* wr = wcih + o*128;
  if (kk < 129){
    float acc = 0.f;
    for (int m = 0; m < 128; ++m) acc += wr[m] * pw[m*129 + kk];
    M2[o*132 + kk] = acc;                       // padded stride 132
  } else {
    float acc = bcih[o] + (o < 256 ? bchh[o] : 0.f);
    for (int m = 0; m < 128; ++m) acc += wr[m] * pb[m];
    b2[o] = acc;
  }
}

// ---------------- K1: table[v][384] = W_ih @ emb[v] + biases (bf16) ----------------
// [r3-v3 exact] Block = 4 waves, 32 vocab rows. Wave w computes o-tiles w*6..w*6+5.
__global__ __launch_bounds__(256, 4)
void table_kernel(const float* __restrict__ emb, const float* __restrict__ wih,
                  const float* __restrict__ bih, const float* __restrict__ bhh,
                  unsigned short* __restrict__ table)
{
  __shared__ unsigned short ebuf[32*128];       // 8KB   [row][k] bf16, chunk-swizzled
  __shared__ unsigned short obuf[32*408];       // 25.5KB [row][384] bf16, padded to 408
  const int tid = threadIdx.x;
  const int w = tid >> 6, lane = tid & 63, c = lane & 15, q = lane >> 4;
  const int vbase = blockIdx.x * 32;

  // stage emb -> ebuf (512 chunks = 32 rows x 16; coalesced 32B loads)
#pragma unroll
  for (int p = 0; p < 2; ++p){
    int chunk = p*256 + tid;
    int row = chunk >> 4, k8 = chunk & 15;
    int va = vbase + row; if (va >= V_VOCAB) va = V_VOCAB - 1;
    const f32x4* src = (const f32x4*)(emb + (size_t)va*128 + k8*8);
    *(bf16x8*)&ebuf[(row*16 + (k8 ^ (row & 15)))*8] = pack8(src[0], src[1]);
  }
  __syncthreads();

  bf16x8 A[2][4];                               // 32 rows x K=128 fragments
#pragma unroll
  for (int rt = 0; rt < 2; ++rt)
#pragma unroll
    for (int kt = 0; kt < 4; ++kt)
      A[rt][kt] = *(const bf16x8*)&ebuf[((rt*16 + c)*16 + ((kt*4 + q) ^ c))*8];

#pragma unroll 1
  for (int j = 0; j < 6; ++j){
    int ot = w*6 + j, o = ot*16 + c;
    bf16x8 Bf[4];
#pragma unroll
    for (int kt = 0; kt < 4; ++kt){
      const f32x4* p = (const f32x4*)(wih + o*128 + kt*32 + q*8);
      Bf[kt] = pack8(p[0], p[1]);
    }
    float bias = bih[o] + (ot < 16 ? bhh[o] : 0.f);   // fold b_hh for r,z gates
    f32x4 D[2];
#pragma unroll
    for (int rt = 0; rt < 2; ++rt) D[rt] = (f32x4){0.f,0.f,0.f,0.f};
#pragma unroll
    for (int kt = 0; kt < 4; ++kt)
#pragma unroll
      for (int rt = 0; rt < 2; ++rt)
        D[rt] = __builtin_amdgcn_mfma_f32_16x16x32_bf16(A[rt][kt], Bf[kt], D[rt], 0,0,0);
#pragma unroll
    for (int rt = 0; rt < 2; ++rt)
#pragma unroll
      for (int r = 0; r < 4; ++r)
        obuf[(rt*16 + q*4 + r)*408 + o] = bf1(D[rt][r] + bias);
  }
  __syncthreads();

  // flush: fully contiguous 16B/lane global stores (1536 chunks = 32 rows x 48)
  const size_t gbase = (size_t)vbase * 384;
#pragma unroll
  for (int i = 0; i < 6; ++i){
    int e8 = i*256 + tid;
    int row = e8 / 48, col8 = e8 % 48;
    if (vbase + row < V_VOCAB)
      *(bf16x8*)&table[gbase + row*384 + col8*8] =
        *(const bf16x8*)&obuf[row*408 + col8*8];
  }
}

// ---------------- K2/K4: GRU recurrence ----------------
// Block = 8 waves = 16 rows. Wave w owns o-cols {w*16..+16} of each gate.
// TABLE path: per step the 16 token rows (16x768B bf16) are staged COALESCED:
//   3 x u64 global loads/thread (issued 3 steps ahead, reg-held) -> ds_write to a
//   776B-stride LDS tile -> 12 conflict-free u16 reads/thread. 1 barrier/step.
// !TABLE path: r3-exact DEPTH-deep gi_f32 prefetch.
template<int STEPS, int DEPTH, bool TABLE_GI, bool FINAL>
__global__ __launch_bounds__(512, 1)
void gru_kernel(const int* __restrict__ tok_ids,
                const unsigned short* __restrict__ gi_tab,
                const float* __restrict__ gi_f32,
                const float* __restrict__ whh,
                const float* __restrict__ bhh,
                const float* __restrict__ hinit,
                float* __restrict__ hout,
                const float* __restrict__ fw,
                const float* __restrict__ fb,
                float* __restrict__ outp)
{
  __shared__ unsigned short hbuf[2][2048];      // [buf][16 rows x 128 k] bf16, swizzled
  __shared__ int toks[2048];                    // token byte-offsets into table
  __shared__ unsigned short gi_lds[2][16*388];  // [buf][16 rows x 388] (776B stride)
  const int tid = threadIdx.x;
  const int w = tid >> 6, lane = tid & 63, c = lane & 15, q = lane >> 4;
  const int n0 = blockIdx.x * 16;

  if constexpr (TABLE_GI){
    for (int i = tid; i < 2048; i += 512) toks[i] = tok_ids[n0*128 + i] * 768;
  }
  // W_hh fragments (B layout: col = lane&15 = o, k = kt*32 + q*8 + e)
  bf16x8 Bw[3][4];
#pragma unroll
  for (int g = 0; g < 3; ++g)
#pragma unroll
    for (int kt = 0; kt < 4; ++kt){
      int o = (g*8 + w)*16 + c;
      const f32x4* p = (const f32x4*)(whh + o*128 + kt*32 + q*8);
      Bw[g][kt] = pack8(p[0], p[1]);
    }
  const float bn = bhh[256 + w*16 + c];         // n-gate hidden bias (multiplied by r)
  float h_old[4];
  {
    float h0 = hinit[w*16 + c];
#pragma unroll
    for (int r = 0; r < 4; ++r) h_old[r] = h0;
  }
  for (int i = tid; i < 2048; i += 512){
    int row = i >> 7, k = i & 127;
    hbuf[0][hchunk(row, k >> 3) + (k & 7)] = bf1(hinit[k]);
  }
  __syncthreads();

  if constexpr (TABLE_GI){
    const char* tb = (const char*)gi_tab;
    // per-thread static staging slots: 1536 x 8B chunks = 16 rows x 768B
    int rowA[3], offB[3];
#pragma unroll
    for (int j = 0; j < 3; ++j){
      int flat = j*512 + tid;
      rowA[j] = flat / 96;                      // 0..15
      offB[j] = (flat % 96) * 8;                // byte offset within the 768B row
    }
    unsigned long long R0[3], R1[3];
    auto load_stage = [&](unsigned long long (&R)[3], int t){
      int tt = t < STEPS ? t : STEPS - 1;       // tail-clamped: uniform count, benign
#pragma unroll
      for (int j = 0; j < 3; ++j)
        R[j] = *(const unsigned long long*)
               (tb + (size_t)(unsigned)toks[rowA[j]*128 + tt] + offB[j]);
    };
    auto write_stage = [&](const unsigned long long (&R)[3], int pb){
#pragma unroll
      for (int j = 0; j < 3; ++j)
        *(unsigned long long*)&gi_lds[pb][rowA[j]*388 + (offB[j] >> 1)] = R[j];
    };
    load_stage(R0, 0);
    load_stage(R1, 1);
    write_stage(R0, 0);                         // vmcnt wait (counted) happens here
    load_stage(R0, 2);
    __syncthreads();                            // gi_lds[0] visible to all

    auto body = [&](int s, unsigned long long (&Rw)[3]){
      const int cur = s & 1, nxt = cur ^ 1;
      bf16x8 A[4];
#pragma unroll
      for (int kt = 0; kt < 4; ++kt)
        A[kt] = *(const bf16x8*)&hbuf[cur][hchunk(c, kt*4 + q)];
      // gi reads: rows q*4+r, cols w*16+c (+128,+256); 776B stride -> conflict-free
      unsigned Gr[4], Gz[4], Gn[4];
#pragma unroll
      for (int r = 0; r < 4; ++r){
        int base = (q*4 + r)*388 + w*16 + c;
        Gr[r] = gi_lds[cur][base];
        Gz[r] = gi_lds[cur][base + 128];
        Gn[r] = gi_lds[cur][base + 256];
      }
      f32x4 D[3];
#pragma unroll
      for (int r = 0; r < 4; ++r){
        D[0][r] = bf2f(Gr[r]);
        D[1][r] = bf2f(Gz[r]);
        D[2][r] = bn;
      }
#pragma unroll
      for (int g = 0; g < 3; ++g)
#pragma unroll
        for (int kt = 0; kt < 4; ++kt)
          D[g] = __builtin_amdgcn_mfma_f32_16x16x32_bf16(A[kt], Bw[g][kt], D[g], 0,0,0);
      // stage pipeline: Rw holds step s+1's rows (issued at s-2) -> LDS for step s+1;
      // then refill Rw with step s+3's rows (stays in flight 2 steps)
      write_stage(Rw, nxt);
      load_stage(Rw, s + 3);
      // gate math: D row = q*4+r, col = c -> lane-local (identical to r3)
#pragma unroll
      for (int r = 0; r < 4; ++r){
        float gn = bf2f(Gn[r]);
        float rr = sigm(D[0][r]);
        float z  = sigm(D[1][r]);
        float nn = tanh_fast(gn + rr * D[2][r]);
        h_old[r] = nn + z*(h_old[r] - nn);
      }
#pragma unroll
      for (int r = 0; r < 4; ++r)
        hbuf[nxt][hchunk(q*4 + r, w*2 + (c >> 3)) + (c & 7)] = bf1(h_old[r]);
      asm volatile("s_waitcnt lgkmcnt(0)" ::: "memory");
      __builtin_amdgcn_s_barrier();
    };
#pragma unroll 1
    for (int s = 0; s < STEPS; s += 2){
      body(s,     R1);                          // even s: flush/refill R1 (t=s+1 / s+3)
      body(s + 1, R0);                          // odd  s: flush/refill R0
    }
  } else {
    unsigned G[DEPTH][12];
    auto load_gi = [&](int d, int S){
#pragma unroll
      for (int r = 0; r < 4; ++r){
        const float* p = gi_f32 + (S*64 + n0 + q*4 + r)*384 + w*16 + c;
        G[d][r]     = __float_as_uint(p[0]);
        G[d][4 + r] = __float_as_uint(p[128]);
        G[d][8 + r] = __float_as_uint(p[256]);
      }
    };
    auto body = [&](int S, int d){
      const int cur = S & 1, nxt = cur ^ 1;
      bf16x8 A[4];
#pragma unroll
      for (int kt = 0; kt < 4; ++kt)
        A[kt] = *(const bf16x8*)&hbuf[cur][hchunk(c, kt*4 + q)];
      f32x4 D[3];
#pragma unroll
      for (int r = 0; r < 4; ++r){
        D[0][r] = __uint_as_float(G[d][r]);
        D[1][r] = __uint_as_float(G[d][4 + r]);
        D[2][r] = bn;
      }
#pragma unroll
      for (int g = 0; g < 3; ++g)
#pragma unroll
        for (int kt = 0; kt < 4; ++kt)
          D[g] = __builtin_amdgcn_mfma_f32_16x16x32_bf16(A[kt], Bw[g][kt], D[g], 0,0,0);
#pragma unroll
      for (int r = 0; r < 4; ++r){
        float gn = __uint_as_float(G[d][8 + r]);
        float rr = sigm(D[0][r]);
        float z  = sigm(D[1][r]);
        float nn = tanh_fast(gn + rr * D[2][r]);
        h_old[r] = nn + z*(h_old[r] - nn);
      }
      if (S + DEPTH < STEPS) load_gi(d, S + DEPTH);
#pragma unroll
      for (int r = 0; r < 4; ++r)
        hbuf[nxt][hchunk(q*4 + r, w*2 + (c >> 3)) + (c & 7)] = bf1(h_old[r]);
      asm volatile("s_waitcnt lgkmcnt(0)" ::: "memory");
      __builtin_amdgcn_s_barrier();
    };
#pragma unroll
    for (int d = 0; d < DEPTH; ++d) load_gi(d, d);
#pragma unroll 1
    for (int s = 0; s < STEPS; s += DEPTH){
#pragma unroll
      for (int d = 0; d < DEPTH; ++d) body(s + d, d);
    }
  }

  if constexpr (FINAL){
    // fused final: out[b][j] = h[b] . fw[j] + fb[j]   (h in hbuf[STEPS&1])
    if (tid < 48){
      int row = tid / 3, j = tid % 3;
      float acc = fb[j];
      const int cur = STEPS & 1;
      for (int k = 0; k < 128; ++k)
        acc += bf2f(hbuf[cur][hchunk(row, k >> 3) + (k & 7)]) * fw[j*128 + k];
      outp[(n0 + row)*3 + j] = acc;
    }
  } else {
#pragma unroll
    for (int r = 0; r < 4; ++r)
      hout[(n0 + q*4 + r)*128 + w*16 + c] = h_old[r];
  }
}

// ---------------- K3: cgi = M2 @ [hT;ind] + b2 ----------------
__global__ __launch_bounds__(256)
void cgi_kernel(const float* __restrict__ hT, const float* __restrict__ M2,
                const float* __restrict__ b2, float* __restrict__ cgi)
{
  const int tid = threadIdx.x;
  const int w = tid >> 6, lane = tid & 63, c = lane & 15, q = lane >> 4;
  const int n0 = (blockIdx.x*4 + w) * 16;       // 200 tiles of 16 rows (n = b*50+c)
  bf16x8 A[4];
#pragma unroll
  for (int kt = 0; kt < 4; ++kt){
    const f32x4* p = (const f32x4*)(hT + (n0 + c)*128 + kt*32 + q*8);
    A[kt] = pack8(p[0], p[1]);
  }
#pragma unroll 1
  for (int ot = 0; ot < 24; ++ot){
    f32x4 D = {0.f,0.f,0.f,0.f};
#pragma unroll
    for (int kt = 0; kt < 4; ++kt){
      const f32x4* p = (const f32x4*)(M2 + (ot*16 + c)*132 + kt*32 + q*8);
      bf16x8 Bf = pack8(p[0], p[1]);
      D = __builtin_amdgcn_mfma_f32_16x16x32_bf16(A[kt], Bf, D, 0,0,0);
    }
    int o = ot*16 + c;
    float bias = b2[o];
    float indv = M2[o*132 + 128];               // conclusion-indicator column
#pragma unroll
    for (int r = 0; r < 4; ++r){
      int n  = n0 + q*4 + r;
      int cc = n % 50, b = n / 50;
      float vv = D[r] + bias + (cc == 0 ? indv : 0.f);
      cgi[(cc*64 + b)*384 + o] = vv;            // stored [c][b] for the ctx scan
    }
  }
}

extern "C" void kernel_launch(void* const* d_in, const int* in_sizes, int n_in,
                              void* d_out, int out_size, void* d_ws, size_t ws_size,
                              hipStream_t stream)
{
  const int*   tok   = (const int*)  d_in[0];
  const float* emb   = (const float*)d_in[1];
  const float* awih  = (const float*)d_in[2];
  const float* awhh  = (const float*)d_in[3];
  const float* abih  = (const float*)d_in[4];
  const float* abhh  = (const float*)d_in[5];
  const float* ainit = (const float*)d_in[6];
  const float* cwih  = (const float*)d_in[7];
  const float* cwhh  = (const float*)d_in[8];
  const float* cbih  = (const float*)d_in[9];
  const float* cbhh  = (const float*)d_in[10];
  const float* cinit = (const float*)d_in[11];
  const float* pw    = (const float*)d_in[12];
  const float* pb    = (const float*)d_in[13];
  const float* fw    = (const float*)d_in[14];
  const float* fb    = (const float*)d_in[15];
  float* out = (float*)d_out;

  char* ws = (char*)d_ws;                       // needs ~83.6 MB
  unsigned short* table = (unsigned short*)(ws + 0);          // 100008*384*2 = 76,806,144
  float* hT  = (float*)(ws + 76806144);                       // 3200*128*4   =  1,638,400
  float* cgi = (float*)(ws + 78444544);                       // 3200*384*4   =  4,915,200
  float* M2  = (float*)(ws + 83359744);                       // 384*132*4    =    202,752
  float* b2  = (float*)(ws + 83562496);                       // 384*4

  m2_kernel   <<<195,  256, 0, stream>>>(cwih, pw, pb, cbih, cbhh, M2, b2);
  table_kernel<<<3126, 256, 0, stream>>>(emb, awih, abih, abhh, table);
  gru_kernel<128, 4, true,  false><<<200, 512, 0, stream>>>(tok, table, nullptr,
                                                            awhh, abhh, ainit, hT,
                                                            nullptr, nullptr, nullptr);
  cgi_kernel  <<<50,   256, 0, stream>>>(hT, M2, b2, cgi);
  gru_kernel<50,  2, false, true ><<<4,   512, 0, stream>>>(nullptr, nullptr, cgi,
                                                            cwhh, cbhh, cinit, nullptr,
                                                            fw, fb, out);
}

// Round 9
// 185.702 us; speedup vs baseline: 1.8391x; 1.3636x over previous
//
#include <hip/hip_runtime.h>

// PosEvalModel: embed-gather + GRU(L=128, N=3200) + proj + GRU(C=50, N=64) + final.
// v9: NO TABLE. W_ih@emb fused into the ast recurrence as a second MFMA chain into the
//     same accumulator, with r3-exact numerics (unscaled bf16 weights, f32 biases as
//     MFMA C-init, proven sigm/tanh_fast) and the r7-proven 3-step LDS staging pipeline
//     for the per-step emb rows.
//  K0 m2:  M2[384][129] = ctx_w_ih @ proj_w (+b2)
//  K1 gru<EMB>: ast recurrence, 8 waves/block/16 rows, 24 MFMA/wave/step;
//      emb rows staged coalesced (f32x4/thread, 2 steps ahead, reg-held) -> bf16 LDS
//      (hchunk layout) -> A-frags; h bf16 in dbuf LDS; 1 barrier/step.
//  K2 cgi: cgi[c,b][384] = M2 @ [hT;ind] + b2
//  K3 gru<!EMB>: ctx recurrence (r7-exact) + fused final matmul epilogue

#define V_VOCAB 100008

typedef __attribute__((ext_vector_type(8))) short bf16x8;
typedef __attribute__((ext_vector_type(4))) float f32x4;

__device__ __forceinline__ unsigned pk_bf16(float lo, float hi){
  unsigned r;
  asm("v_cvt_pk_bf16_f32 %0, %1, %2" : "=v"(r) : "v"(lo), "v"(hi));
  return r;
}
__device__ __forceinline__ unsigned short bf1(float x){   // f32->bf16 via HW cvt
  return (unsigned short)pk_bf16(x, x);
}
__device__ __forceinline__ bf16x8 pack8(f32x4 a, f32x4 b){
  union { unsigned u[4]; bf16x8 v; } x;
  x.u[0] = pk_bf16(a[0], a[1]);
  x.u[1] = pk_bf16(a[2], a[3]);
  x.u[2] = pk_bf16(b[0], b[1]);
  x.u[3] = pk_bf16(b[2], b[3]);
  return x.v;
}
__device__ __forceinline__ float bf2f(unsigned bits){
  union { unsigned u; float f; } x; x.u = bits << 16; return x.f;
}
__device__ __forceinline__ float fexp2(float x){ return __builtin_amdgcn_exp2f(x); }
__device__ __forceinline__ float frcp(float x){ return __builtin_amdgcn_rcpf(x); }
__device__ __forceinline__ float sigm(float x){ return frcp(1.f + fexp2(x * -1.44269504089f)); }
__device__ __forceinline__ float tanh_fast(float x){
  float t = fexp2(x * -2.88539008178f);        // e^{-2x}
  return (1.f - t) * frcp(1.f + t);
}
// element index of the 8-elem chunk (row, ch=k>>3) in a 16x128 bf16 tile, swizzled
__device__ __forceinline__ int hchunk(int row, int ch){
  return row*128 + ((ch ^ row ^ (row >> 2)) & 15)*8;
}

// ---------------- K0: M2 = ctx_w_ih @ proj_w (+b2) ----------------
__global__ __launch_bounds__(256)
void m2_kernel(const float* __restrict__ wcih, const float* __restrict__ pw,
               const float* __restrict__ pb, const float* __restrict__ bcih,
               const float* __restrict__ bchh, float* __restrict__ M2,
               float* __restrict__ b2)
{
  int t = blockIdx.x*256 + threadIdx.x;
  if (t >= 384*130) return;
  int o = t / 130, kk = t % 130;
  const float* wr = wcih + o*128;
  if (kk < 129){
    float acc = 0.f;
    for (int m = 0; m < 128; ++m) acc += wr[m] * pw[m*129 + kk];
    M2[o*132 + kk] = acc;                       // padded stride 132
  } else {
    float acc = bcih[o] + (o < 256 ? bchh[o] : 0.f);
    for (int m = 0; m < 128; ++m) acc += wr[m] * pb[m];
    b2[o] = acc;
  }
}

// ---------------- K1/K3: GRU recurrence ----------------
// Block = 8 waves = 16 rows. Wave w owns gate-cols {w*16..w*16+15} (r,z,n).
// EMB: D = mfma(Ax,Bx, mfma(Ah,Bh, C=f32 bias)); emb rows for step s+1 staged via the
//   r7-proven 3-step pipeline (coalesced f32x4 load 2 steps ahead -> regs -> ds_write
//   into xbuf[nxt] -> read next step). All weights bf16 UNSCALED; gates r3-exact.
// !EMB: r7-exact DEPTH-deep gi_f32 prefetch (ctx path).
template<int STEPS, int DEPTH, bool EMB, bool FINAL>
__global__ __launch_bounds__(512, 1)
void gru_kernel(const int* __restrict__ tok_ids,
                const float* __restrict__ emb,
                const float* __restrict__ gi_f32,
                const float* __restrict__ whh,
                const float* __restrict__ wih,
                const float* __restrict__ bih,
                const float* __restrict__ bhh,
                const float* __restrict__ hinit,
                float* __restrict__ hout,
                const float* __restrict__ fw,
                const float* __restrict__ fb,
                float* __restrict__ outp)
{
  __shared__ unsigned short hbuf[2][2048];      // [buf][16 rows x 128 k] bf16, swizzled
  __shared__ int toks[EMB ? 2048 : 2];          // emb byte-offsets [16 rows][128 steps]
  __shared__ unsigned short xbuf[EMB ? 4096 : 2]; // [buf][16 x 128] bf16 emb, swizzled
  const int tid = threadIdx.x;
  const int w = tid >> 6, lane = tid & 63, c = lane & 15, q = lane >> 4;
  const int n0 = blockIdx.x * 16;
  const int w16c = w*16 + c;

  if constexpr (EMB){
    for (int i = tid; i < 2048; i += 512) toks[i] = tok_ids[n0*128 + i] << 9;  // *512B
  }
  // weight fragments, UNSCALED bf16 (B layout: col = lane&15 = o, k = kt*32 + q*8 + e)
  bf16x8 Bh[3][4], Bx[3][4];
#pragma unroll
  for (int g = 0; g < 3; ++g)
#pragma unroll
    for (int kt = 0; kt < 4; ++kt){
      int o = g*128 + w16c;
      const f32x4* ph = (const f32x4*)(whh + o*128 + kt*32 + q*8);
      Bh[g][kt] = pack8(ph[0], ph[1]);
      if constexpr (EMB){
        const f32x4* px = (const f32x4*)(wih + o*128 + kt*32 + q*8);
        Bx[g][kt] = pack8(px[0], px[1]);
      }
    }
  float cr, cz, cin;
  const float bn = bhh[256 + w16c];             // b_hh_n (multiplied by r)
  if constexpr (EMB){
    cr  = bih[w16c]       + bhh[w16c];          // b_ih_r + b_hh_r
    cz  = bih[128 + w16c] + bhh[128 + w16c];    // b_ih_z + b_hh_z
    cin = bih[256 + w16c];                      // b_ih_n (outside r*(...))
  }
  float h_old[4];
  {
    float h0 = hinit[w16c];
#pragma unroll
    for (int r = 0; r < 4; ++r) h_old[r] = h0;
  }
  for (int i = tid; i < 2048; i += 512){
    int row = i >> 7, k = i & 127;
    hbuf[0][hchunk(row, k >> 3) + (k & 7)] = bf1(hinit[k]);
  }
  __syncthreads();

  if constexpr (EMB){
    // stager slot: 512 threads = 16 rows x 32 f32x4 chunks
    const int srow = tid >> 5, spos = tid & 31;
    const int sdst = hchunk(srow, spos >> 1) + (spos & 1)*4;  // 8B-aligned short idx
    f32x4 E0, E1;
    auto load_x = [&](f32x4& E, int t){
      int tt = t < STEPS ? t : STEPS - 1;       // tail-clamped, uniform count
      E = *(const f32x4*)((const char*)emb
            + (size_t)(unsigned)toks[srow*128 + tt] + spos*16);
    };
    auto write_x = [&](const f32x4& E, int b){
      unsigned long long v = ((unsigned long long)pk_bf16(E[2], E[3]) << 32)
                           | pk_bf16(E[0], E[1]);
      *(unsigned long long*)&xbuf[b*2048 + sdst] = v;
    };
    load_x(E0, 0);
    load_x(E1, 1);
    write_x(E0, 0);                             // compiler-counted vmcnt wait here
    load_x(E0, 2);
    __syncthreads();                            // xbuf[0] visible to all

    auto body = [&](int s, f32x4& Ew){
      const int cur = s & 1, nxt = cur ^ 1;
      bf16x8 Ah[4], Ax[4];
#pragma unroll
      for (int kt = 0; kt < 4; ++kt){
        Ah[kt] = *(const bf16x8*)&hbuf[cur][hchunk(c, kt*4 + q)];
        Ax[kt] = *(const bf16x8*)&xbuf[cur*2048 + hchunk(c, kt*4 + q)];
      }
      f32x4 D0, D1, D2, D3;
#pragma unroll
      for (int r = 0; r < 4; ++r){ D0[r] = cr; D1[r] = cz; D2[r] = bn; D3[r] = cin; }
#pragma unroll
      for (int kt = 0; kt < 4; ++kt){
        D0 = __builtin_amdgcn_mfma_f32_16x16x32_bf16(Ax[kt], Bx[0][kt], D0, 0,0,0);
        D1 = __builtin_amdgcn_mfma_f32_16x16x32_bf16(Ax[kt], Bx[1][kt], D1, 0,0,0);
        D3 = __builtin_amdgcn_mfma_f32_16x16x32_bf16(Ax[kt], Bx[2][kt], D3, 0,0,0);
        D0 = __builtin_amdgcn_mfma_f32_16x16x32_bf16(Ah[kt], Bh[0][kt], D0, 0,0,0);
        D1 = __builtin_amdgcn_mfma_f32_16x16x32_bf16(Ah[kt], Bh[1][kt], D1, 0,0,0);
        D2 = __builtin_amdgcn_mfma_f32_16x16x32_bf16(Ah[kt], Bh[2][kt], D2, 0,0,0);
      }
      // pipeline: Ew holds step s+1's emb (loaded at s-2) -> xbuf for s+1; refill s+3
      write_x(Ew, nxt);
      load_x(Ew, s + 3);
      // gates: r3-exact (D row = q*4+r, col = c -> lane-local)
#pragma unroll
      for (int r = 0; r < 4; ++r){
        float rr = sigm(D0[r]);
        float z  = sigm(D1[r]);
        float nn = tanh_fast(D3[r] + rr * D2[r]);
        h_old[r] = nn + z*(h_old[r] - nn);
      }
#pragma unroll
      for (int r = 0; r < 4; ++r)
        hbuf[nxt][hchunk(q*4 + r, w*2 + (c >> 3)) + (c & 7)] = bf1(h_old[r]);
      asm volatile("s_waitcnt lgkmcnt(0)" ::: "memory");
      __builtin_amdgcn_s_barrier();
    };
#pragma unroll 1
    for (int s = 0; s < STEPS; s += 2){
      body(s,     E1);                          // even s: flush/refill E1 (t=s+1 / s+3)
      body(s + 1, E0);                          // odd  s: flush/refill E0
    }
  } else {
    unsigned G[DEPTH][12];
    auto load_gi = [&](int d, int S){
#pragma unroll
      for (int r = 0; r < 4; ++r){
        const float* p = gi_f32 + (S*64 + n0 + q*4 + r)*384 + w16c;
        G[d][r]     = __float_as_uint(p[0]);
        G[d][4 + r] = __float_as_uint(p[128]);
        G[d][8 + r] = __float_as_uint(p[256]);
      }
    };
    auto body = [&](int S, int d){
      const int cur = S & 1, nxt = cur ^ 1;
      bf16x8 A[4];
#pragma unroll
      for (int kt = 0; kt < 4; ++kt)
        A[kt] = *(const bf16x8*)&hbuf[cur][hchunk(c, kt*4 + q)];
      f32x4 D[3];
#pragma unroll
      for (int r = 0; r < 4; ++r){
        D[0][r] = __uint_as_float(G[d][r]);
        D[1][r] = __uint_as_float(G[d][4 + r]);
        D[2][r] = bn;
      }
#pragma unroll
      for (int g = 0; g < 3; ++g)
#pragma unroll
        for (int kt = 0; kt < 4; ++kt)
          D[g] = __builtin_amdgcn_mfma_f32_16x16x32_bf16(A[kt], Bh[g][kt], D[g], 0,0,0);
#pragma unroll
      for (int r = 0; r < 4; ++r){
        float gn = __uint_as_float(G[d][8 + r]);
        float rr = sigm(D[0][r]);
        float z  = sigm(D[1][r]);
        float nn = tanh_fast(gn + rr * D[2][r]);
        h_old[r] = nn + z*(h_old[r] - nn);
      }
      if (S + DEPTH < STEPS) load_gi(d, S + DEPTH);
#pragma unroll
      for (int r = 0; r < 4; ++r)
        hbuf[nxt][hchunk(q*4 + r, w*2 + (c >> 3)) + (c & 7)] = bf1(h_old[r]);
      asm volatile("s_waitcnt lgkmcnt(0)" ::: "memory");
      __builtin_amdgcn_s_barrier();
    };
#pragma unroll
    for (int d = 0; d < DEPTH; ++d) load_gi(d, d);
#pragma unroll 1
    for (int s = 0; s < STEPS; s += DEPTH){
#pragma unroll
      for (int d = 0; d < DEPTH; ++d) body(s + d, d);
    }
  }

  if constexpr (FINAL){
    // fused final: out[b][j] = h[b] . fw[j] + fb[j]   (h in hbuf[STEPS&1])
    if (tid < 48){
      int row = tid / 3, j = tid % 3;
      float acc = fb[j];
      const int cur = STEPS & 1;
      for (int k = 0; k < 128; ++k)
        acc += bf2f(hbuf[cur][hchunk(row, k >> 3) + (k & 7)]) * fw[j*128 + k];
      outp[(n0 + row)*3 + j] = acc;
    }
  } else {
#pragma unroll
    for (int r = 0; r < 4; ++r)
      hout[(n0 + q*4 + r)*128 + w16c] = h_old[r];
  }
}

// ---------------- K2: cgi = M2 @ [hT;ind] + b2 ----------------
__global__ __launch_bounds__(256)
void cgi_kernel(const float* __restrict__ hT, const float* __restrict__ M2,
                const float* __restrict__ b2, float* __restrict__ cgi)
{
  const int tid = threadIdx.x;
  const int w = tid >> 6, lane = tid & 63, c = lane & 15, q = lane >> 4;
  const int n0 = (blockIdx.x*4 + w) * 16;       // 200 tiles of 16 rows (n = b*50+c)
  bf16x8 A[4];
#pragma unroll
  for (int kt = 0; kt < 4; ++kt){
    const f32x4* p = (const f32x4*)(hT + (n0 + c)*128 + kt*32 + q*8);
    A[kt] = pack8(p[0], p[1]);
  }
#pragma unroll 1
  for (int ot = 0; ot < 24; ++ot){
    f32x4 D = {0.f,0.f,0.f,0.f};
#pragma unroll
    for (int kt = 0; kt < 4; ++kt){
      const f32x4* p = (const f32x4*)(M2 + (ot*16 + c)*132 + kt*32 + q*8);
      bf16x8 Bf = pack8(p[0], p[1]);
      D = __builtin_amdgcn_mfma_f32_16x16x32_bf16(A[kt], Bf, D, 0,0,0);
    }
    int o = ot*16 + c;
    float bias = b2[o];
    float indv = M2[o*132 + 128];               // conclusion-indicator column
#pragma unroll
    for (int r = 0; r < 4; ++r){
      int n  = n0 + q*4 + r;
      int cc = n % 50, b = n / 50;
      float vv = D[r] + bias + (cc == 0 ? indv : 0.f);
      cgi[(cc*64 + b)*384 + o] = vv;            // stored [c][b] for the ctx scan
    }
  }
}

extern "C" void kernel_launch(void* const* d_in, const int* in_sizes, int n_in,
                              void* d_out, int out_size, void* d_ws, size_t ws_size,
                              hipStream_t stream)
{
  const int*   tok   = (const int*)  d_in[0];
  const float* emb   = (const float*)d_in[1];
  const float* awih  = (const float*)d_in[2];
  const float* awhh  = (const float*)d_in[3];
  const float* abih  = (const float*)d_in[4];
  const float* abhh  = (const float*)d_in[5];
  const float* ainit = (const float*)d_in[6];
  const float* cwih  = (const float*)d_in[7];
  const float* cwhh  = (const float*)d_in[8];
  const float* cbih  = (const float*)d_in[9];
  const float* cbhh  = (const float*)d_in[10];
  const float* cinit = (const float*)d_in[11];
  const float* pw    = (const float*)d_in[12];
  const float* pb    = (const float*)d_in[13];
  const float* fw    = (const float*)d_in[14];
  const float* fb    = (const float*)d_in[15];
  float* out = (float*)d_out;

  char* ws = (char*)d_ws;                       // needs ~6.8 MB
  float* hT  = (float*)(ws + 0);                              // 3200*128*4 = 1,638,400
  float* cgi = (float*)(ws + 1638400);                        // 3200*384*4 = 4,915,200
  float* M2  = (float*)(ws + 6553600);                        // 384*132*4  =   202,752
  float* b2  = (float*)(ws + 6756352);                        // 384*4

  m2_kernel<<<195, 256, 0, stream>>>(cwih, pw, pb, cbih, cbhh, M2, b2);
  gru_kernel<128, 2, true,  false><<<200, 512, 0, stream>>>(
      tok, emb, nullptr, awhh, awih, abih, abhh, ainit, hT, nullptr, nullptr, nullptr);
  cgi_kernel<<<50, 256, 0, stream>>>(hT, M2, b2, cgi);
  gru_kernel<50,  2, false, true ><<<4,   512, 0, stream>>>(
      nullptr, nullptr, cgi, cwhh, nullptr, nullptr, cbhh, cinit, nullptr, fw, fb, out);
}